// Round 20
// baseline (74.198 us; speedup 1.0000x reference)
//
#include <hip/hip_runtime.h>

#define NV 1448
#define JD 4344     // 3*NV
#define CC 256
#define BB 64
#define QQ 128      // 2*BB
#define NP 1472     // 46 tiles of 32 (pads carry |p|^2 = 60000)
#define PADV 60000.0f

typedef __bf16    bf16x8 __attribute__((ext_vector_type(8)));
typedef _Float16  f16x8  __attribute__((ext_vector_type(8)));
typedef float     f32x4  __attribute__((ext_vector_type(4)));
typedef float     f32x16 __attribute__((ext_vector_type(16)));

__device__ __forceinline__ unsigned f2bf(float f) {
    unsigned u = __float_as_uint(f);
    return (u + 0x7FFFu + ((u >> 16) & 1u)) >> 16;
}
union HU { _Float16 h; unsigned short u; };
__device__ __forceinline__ unsigned short f2h(float f) { HU t; t.h = (_Float16)f; return t.u; }
__device__ __forceinline__ float h2f(unsigned short u) { HU t; t.u = u; return (float)t.h; }

#define MIN3A(dst, a, b) asm("v_min3_f32 %0, %0, %1, %2" : "+v"(dst) : "v"(a), "v"(b))

// ---------------------------------------------------------------------------
// K1: global average pool -> latQb[q][c] (bf16). Thread 0 zeroes acc.
// ---------------------------------------------------------------------------
__global__ __launch_bounds__(256) void pool_kernel(const float* __restrict__ inp,
                                                   const float* __restrict__ tgt,
                                                   unsigned short* __restrict__ latQb,
                                                   unsigned long long* __restrict__ acc) {
    int gid  = blockIdx.x * 256 + threadIdx.x;
    if (gid == 0) { acc[0] = 0ull; acc[1] = 0ull; }
    int lane = gid & 15;
    int row  = gid >> 4;
    if (row >= 2 * BB * CC) return;
    int t  = row >> 14;
    int bc = row & 16383;
    const float* src = (t ? tgt : inp) + (size_t)bc * 64;
    float4 v = reinterpret_cast<const float4*>(src)[lane];
    float s = (v.x + v.y) + (v.z + v.w);
    s += __shfl_xor(s, 1);
    s += __shfl_xor(s, 2);
    s += __shfl_xor(s, 4);
    s += __shfl_xor(s, 8);
    if (lane == 0) {
        int b = bc >> 8, c = bc & 255;
        latQb[(size_t)(t * 64 + b) * CC + c] = (unsigned short)f2bf(s * (1.0f / 64.0f));
    }
}

// ---------------------------------------------------------------------------
// K2: decode GEMM via bf16 MFMA (R15, proven bit-exact).
// ---------------------------------------------------------------------------
__global__ __launch_bounds__(256) void decode_kernel(const unsigned short* __restrict__ latQb,
                                                     const float* __restrict__ muL,
                                                     const float* __restrict__ deltaL,
                                                     const float* __restrict__ muR,
                                                     const float* __restrict__ deltaR,
                                                     const int* __restrict__ labels,
                                                     float* __restrict__ pts3) {
    const int jt   = blockIdx.x;
    const int side = blockIdx.y;
    const int qq   = blockIdx.z;
    const float* __restrict__ delta = side ? deltaR : deltaL;
    const float* __restrict__ mu    = side ? muR : muL;
    const int jb = jt * 64;
    const int q0 = qq * 32;
    const int tid  = threadIdx.x;
    const int w    = tid >> 6;
    const int lane = tid & 63;

    __shared__ unsigned short dB[64 * 264];
    __shared__ unsigned short lB[32 * 264];

#pragma unroll
    for (int i = 0; i < 16; ++i) {
        int idx = i * 256 + tid;
        int row = idx >> 6;
        int ch  = idx & 63;
        int j   = jb + row;
        unsigned u0 = 0, u1 = 0;
        if (j < JD) {
            float4 v = *reinterpret_cast<const float4*>(delta + (size_t)j * CC + ch * 4);
            u0 = f2bf(v.x) | (f2bf(v.y) << 16);
            u1 = f2bf(v.z) | (f2bf(v.w) << 16);
        }
        *reinterpret_cast<uint2*>(&dB[row * 264 + ch * 4]) = make_uint2(u0, u1);
    }
#pragma unroll
    for (int i = 0; i < 4; ++i) {
        int idx = i * 256 + tid;
        int row = idx >> 5;
        int ch  = idx & 31;
        *reinterpret_cast<uint4*>(&lB[row * 264 + ch * 8]) =
            *reinterpret_cast<const uint4*>(latQb + (size_t)(q0 + row) * CC + ch * 8);
    }
    __syncthreads();

    const int col  = lane & 15;
    const int kgrp = lane >> 4;
    bf16x8 bfr[8];
#pragma unroll
    for (int ks = 0; ks < 8; ++ks)
        bfr[ks] = *reinterpret_cast<const bf16x8*>(&dB[(w * 16 + col) * 264 + ks * 32 + kgrp * 8]);

    int j = jb + w * 16 + col;
    float muv = (j < JD) ? mu[j] : 0.f;

#pragma unroll
    for (int mt = 0; mt < 2; ++mt) {
        f32x4 acc = {0.f, 0.f, 0.f, 0.f};
#pragma unroll
        for (int ks = 0; ks < 8; ++ks) {
            bf16x8 a = *reinterpret_cast<const bf16x8*>(&lB[(mt * 16 + col) * 264 + ks * 32 + kgrp * 8]);
            acc = __builtin_amdgcn_mfma_f32_16x16x32_bf16(a, bfr[ks], acc, 0, 0, 0);
        }
        if (j < JD) {
#pragma unroll
            for (int r = 0; r < 4; ++r) {
                int q = q0 + mt * 16 + kgrp * 4 + r;
                if (labels[q & 63] == side)
                    pts3[(size_t)q * JD + j] = acc[r] + muv;
            }
        }
    }
}

// ---------------------------------------------------------------------------
// K2b: pack BOTH encodings per point (R16/R17 slot math, absmax-0 proven):
//  A-enc: [ahx ahx alx ahy ahy aly ahz ahz alz 1 1 a2h a2l 0 0 0]
//  B-enc: [bhx blx bhx bhy bly bhy bhz blz bhz b2h b2l 1 1 0 0 0]
//  dot(A,B) = -2 a.b + |b|^2 + |a|^2 = d^2 (fp32-emulated in fp16 pairs).
//  packA[q] = A-enc(point q);  packB[q^64] = B-enc(point q), so chamfer
//  block (b,dir) reads rows packA[dir*64+b] vs cols packB[dir*64+b].
// ---------------------------------------------------------------------------
__global__ __launch_bounds__(256) void pack_kernel(const float* __restrict__ pts3,
                                                   unsigned short* __restrict__ packA,
                                                   unsigned short* __restrict__ packB) {
    int idx = blockIdx.x * 256 + threadIdx.x;   // 128*1472 = 188416 = 736*256
    if (idx >= QQ * NP) return;
    int q = idx / NP;
    int n = idx - q * NP;
    float x = 0.f, y = 0.f, z = 0.f;
    bool real = n < NV;
    if (real) {
        const float* p = pts3 + (size_t)q * JD + n * 3;
        x = p[0]; y = p[1]; z = p[2];
    }
    float p2 = fmaf(x, x, fmaf(y, y, z * z));
    if (!real) p2 = PADV;
    unsigned short p2h = f2h(p2);
    unsigned short p2l = f2h(p2 - h2f(p2h));
    unsigned short one = f2h(1.0f);

    unsigned short ahx = f2h(-2.f * x), ahy = f2h(-2.f * y), ahz = f2h(-2.f * z);
    unsigned short alx = f2h(-2.f * x - h2f(ahx));
    unsigned short aly = f2h(-2.f * y - h2f(ahy));
    unsigned short alz = f2h(-2.f * z - h2f(ahz));
    unsigned short outA[16] = {ahx, ahx, alx, ahy, ahy, aly, ahz, ahz, alz,
                               one, one, p2h, p2l, 0, 0, 0};
    uint4* dA = reinterpret_cast<uint4*>(packA + ((size_t)q * NP + n) * 16);
    dA[0] = *reinterpret_cast<uint4*>(&outA[0]);
    dA[1] = *reinterpret_cast<uint4*>(&outA[8]);

    unsigned short bhx = f2h(x), bhy = f2h(y), bhz = f2h(z);
    unsigned short blx = f2h(x - h2f(bhx));
    unsigned short bly = f2h(y - h2f(bhy));
    unsigned short blz = f2h(z - h2f(bhz));
    unsigned short outB[16] = {bhx, blx, bhx, bhy, bly, bhy, bhz, blz, bhz,
                               p2h, p2l, one, one, 0, 0, 0};
    uint4* dB = reinterpret_cast<uint4*>(packB + ((size_t)(q ^ 64) * NP + n) * 16);
    dB[0] = *reinterpret_cast<uint4*>(&outB[0]);
    dB[1] = *reinterpret_cast<uint4*>(&outB[8]);
}

// ---------------------------------------------------------------------------
// K3: chamfer via 32x32x16 f16 MFMA — ROW-MINS ONLY, one pass per direction.
// grid (b 0..63, dir 0..1, rslice 0..7) = 1024 blocks x 256 thr.
// PLAIN launch bounds (every (256,2) variant failed correctness; every
// plain-bounds MFMA kernel passed). LDS = 47104+17408+16 = 64528 B <= 64KB.
// 46 tile-cols split 12/12/11/11 across waves with wave-uniform guards;
// all register arrays statically indexed (no scratch). 2-deep MFMA batch
// (R17-proven). rmw merge + countdown finalize (R17-proven).
// ---------------------------------------------------------------------------
__global__ __launch_bounds__(256) void chamfer_kernel(const unsigned short* __restrict__ packA,
                                                      const unsigned short* __restrict__ packB,
                                                      unsigned long long* __restrict__ acc,
                                                      float* __restrict__ out) {
    const int b      = blockIdx.x;
    const int dir    = blockIdx.y;
    const int rslice = blockIdx.z;
    const int ntr    = (rslice == 7) ? 4 : 6;    // 46 = 7*6 + 4
    const int tid  = threadIdx.x;
    const int w    = tid >> 6;
    const int lane = tid & 63;
    const int col  = lane & 31;
    const int half = lane >> 5;
    const size_t pb = (size_t)(dir * BB + b) * NP;

    __shared__ unsigned short BsL[NP * 16];   // 47104 B, XOR-swizzled
    __shared__ float rmw[4][64][17];          // 17408 B
    __shared__ float wsum[4];

    {   // stage B: 2944 uint4, swizzled (write & read same bijection)
        const uint4* src = reinterpret_cast<const uint4*>(packB + pb * 16);
        uint4* dst = reinterpret_cast<uint4*>(BsL);
        for (int i = tid; i < NP * 2; i += 256)
            dst[i ^ ((i >> 3) & 7)] = src[i];
    }
    __syncthreads();

    // wave's tile-col range: {0,11,23,34} .. {11,23,34,46} = 11/12/11/12 cols
    const int tc0 = (w * 46) >> 2;
    const int tc1 = ((w + 1) * 46) >> 2;

    f32x16 zero16;
#pragma unroll
    for (int i = 0; i < 16; ++i) zero16[i] = 0.f;

    float ssum = 0.f;
    const char* Bb = (const char*)BsL;
    const char* Ab = (const char*)packA;

    for (int trl = 0; trl < ntr; ++trl) {
        const int tr = rslice * 6 + trl;
        f16x8 afr = *reinterpret_cast<const f16x8*>(
            Ab + (pb + (size_t)(tr * 32 + col)) * 32 + half * 16);

        float rm[16];
#pragma unroll
        for (int i = 0; i < 16; ++i) rm[i] = 1e30f;

#pragma unroll
        for (int p = 0; p < 6; ++p) {          // up to 12 cols as 2-batches
            int tc = tc0 + 2 * p;
            if (tc + 1 < tc1) {
                int t0i = tc * 64 + col * 2 + half;
                int t1i = t0i + 64;
                f16x8 bf0 = *reinterpret_cast<const f16x8*>(Bb + 16 * (t0i ^ ((t0i >> 3) & 7)));
                f16x8 bf1 = *reinterpret_cast<const f16x8*>(Bb + 16 * (t1i ^ ((t1i >> 3) & 7)));
                f32x16 d0 = __builtin_amdgcn_mfma_f32_32x32x16_f16(afr, bf0, zero16, 0, 0, 0);
                f32x16 d1 = __builtin_amdgcn_mfma_f32_32x32x16_f16(afr, bf1, zero16, 0, 0, 0);
#pragma unroll
                for (int i = 0; i < 16; ++i)
                    MIN3A(rm[i], d0[i], d1[i]);
            } else if (tc < tc1) {             // odd tail (11-col waves)
                int t0i = tc * 64 + col * 2 + half;
                f16x8 bf0 = *reinterpret_cast<const f16x8*>(Bb + 16 * (t0i ^ ((t0i >> 3) & 7)));
                f32x16 d0 = __builtin_amdgcn_mfma_f32_32x32x16_f16(afr, bf0, zero16, 0, 0, 0);
#pragma unroll
                for (int i = 0; i < 16; ++i) rm[i] = fminf(rm[i], d0[i]);
            }
        }

        // cross-wave/cross-col row-min merge for these 32 rows (R17-proven)
#pragma unroll
        for (int i = 0; i < 16; ++i) rmw[w][lane][i] = rm[i];
        __syncthreads();
        {
            int R = tid >> 3, k = tid & 7;            // 32 rows x 8 helpers
            int reg = (R & 3) | ((R >> 3) << 2);
            int h   = (R >> 2) & 1;
            float v = 1e30f;
#pragma unroll
            for (int ww = 0; ww < 4; ++ww) {
                v = fminf(v, rmw[ww][h * 32 + k][reg]);
                v = fminf(v, rmw[ww][h * 32 + k + 8][reg]);
                v = fminf(v, rmw[ww][h * 32 + k + 16][reg]);
                v = fminf(v, rmw[ww][h * 32 + k + 24][reg]);
            }
            v = fminf(v, __shfl_xor(v, 1));
            v = fminf(v, __shfl_xor(v, 2));
            v = fminf(v, __shfl_xor(v, 4));
            if (k == 0) {
                int row = tr * 32 + R;
                if (row < NV) ssum += sqrtf(fmaxf(v, 1e-12f));
            }
        }
        __syncthreads();
    }

    // block sum -> fixed-point atomic; last of 1024 blocks writes out
    ssum += __shfl_xor(ssum, 1);
    ssum += __shfl_xor(ssum, 2);
    ssum += __shfl_xor(ssum, 4);
    ssum += __shfl_xor(ssum, 8);
    ssum += __shfl_xor(ssum, 16);
    ssum += __shfl_xor(ssum, 32);
    if ((tid & 63) == 0) wsum[w] = ssum;
    __syncthreads();
    if (tid == 0) {
        float bs = (wsum[0] + wsum[1]) + (wsum[2] + wsum[3]);
        atomicAdd(acc, (unsigned long long)((double)bs * 16777216.0));
        __threadfence();
        unsigned long long done = atomicAdd(acc + 1, 1ull);
        if (done == 1023) {
            __threadfence();
            unsigned long long total = atomicAdd(acc, 0ull);
            out[0] = (float)((double)total * (0x1p-24 / (64.0 * 1448.0)));
        }
    }
}

extern "C" void kernel_launch(void* const* d_in, const int* in_sizes, int n_in,
                              void* d_out, int out_size, void* d_ws, size_t ws_size,
                              hipStream_t stream) {
    const float* inp    = (const float*)d_in[0];
    const float* tgt    = (const float*)d_in[1];
    const int*   labels = (const int*)d_in[2];
    const float* muL    = (const float*)d_in[3];
    const float* deltaL = (const float*)d_in[4];
    const float* muR    = (const float*)d_in[5];
    const float* deltaR = (const float*)d_in[6];
    float* out = (float*)d_out;

    char* ws = (char*)d_ws;
    unsigned short* latQb = (unsigned short*)ws;                      // 65536 B
    float* pts3           = (float*)(ws + 65536);                     // 2224128 B
    unsigned short* packA = (unsigned short*)(ws + 2289664);          // 128*1472*32 = 6029312 B
    unsigned short* packB = (unsigned short*)(ws + 8318976);          // 6029312 B
    unsigned long long* acc = (unsigned long long*)(ws + 14348288);   // 16 B

    hipLaunchKernelGGL(pool_kernel, dim3(2048), dim3(256), 0, stream, inp, tgt, latQb, acc);
    hipLaunchKernelGGL(decode_kernel, dim3(68, 2, 4), dim3(256), 0, stream,
                       latQb, muL, deltaL, muR, deltaR, labels, pts3);
    hipLaunchKernelGGL(pack_kernel, dim3(736), dim3(256), 0, stream, pts3, packA, packB);
    hipLaunchKernelGGL(chamfer_kernel, dim3(BB, 2, 8), dim3(256), 0, stream,
                       packA, packB, acc, out);
}